// Round 7
// baseline (211.730 us; speedup 1.0000x reference)
//
#include <hip/hip_runtime.h>
#include <hip/hip_fp16.h>
#include <cmath>

#define NLOD 10

// ---------------------------------------------------------------------------
// LDS layout -- dual 4B-stride tables per level (round-6 decision):
//   per level L:  [T01: SIZE x half2 (f0,f1)] [T2: SIZE x float f2]
//   level byte base = ENT[L] * 8  (8 B/entry total, same 78040 B footprint)
//
// WHY: the 8 B AoS entry made every gather a ds_read_b64 whose dword address
// idx*2 is always EVEN -> 64 lanes hit only 16 of 32 LDS banks (measured
// 1.6e7 conflict cycles = 62% of LDS-pipe time, the binding pipe).  With two
// 4B-stride tables, bank = idx % 32 uses all 32 banks; both reads stay
// DWORD-granular (round 4 proved sub-dword reads serialize).  One shared
// offset o4 = idx*4 feeds both reads; T2 sits at compile-time immediate
// SIZE*4 from T01.  f2 is exact f32 now (accuracy can only improve).
//
// Order: hashed levels first (immediates <= 34504 < 65536); dense grids
// after, their level base folded INTO the float address fma for free.
//
// Scheduling lesson (R2/R3/R6): hipcc re-serializes any source-phased load
// structure at low VGPR budget and spills at high pressure -- keep the
// immediate-consume form and the full 2-blocks/CU occupancy (1024,8).
// ---------------------------------------------------------------------------
static constexpr int HSIZES[6] = {324, 529, 900, 1024, 1024, 1024}; // levels 4..9
static constexpr int HENT[6]   = {0, 324, 853, 1753, 2777, 3801};   // entry offsets
static constexpr int TOTAL_ENTRIES = 9755;                           // 4825 + 4930
// dense grids: res 7,8,11,14 -> cubes 343,512,1331,2744; entry offsets:
//   4825, 5168, 5680, 7011.   LDS bytes = 9755 * 8 = 78040.

struct ResArr { int r[NLOD]; };

// f0,f1 from the packed half2 via v_fma_mix op_sel (exact fused f16->f32 fma);
// f2 is plain f32 -> ordinary fmaf.
__device__ __forceinline__ void corner_accum(unsigned r01, float r2, float wt,
                                             float& a0, float& a1, float& a2)
{
    asm("v_fma_mix_f32 %0, %1, %2, %0 op_sel_hi:[1,0,0]"
        : "+v"(a0) : "v"(r01), "v"(wt));
    asm("v_fma_mix_f32 %0, %1, %2, %0 op_sel:[1,0,0] op_sel_hi:[1,0,0]"
        : "+v"(a1) : "v"(r01), "v"(wt));
    a2 = fmaf(r2, wt, a2);
}

// ---------------------------------------------------------------------------
// Dense (de-hashed) levels 0..3.  LEVELBASE (byte) is folded into the float
// address chain: a = gx*(R^2*4) + gy*(R*4) + gz*4 + LEVELBASE, exact integer
// arithmetic in f32 (all partial sums < 2^24).  Corner deltas and the T2
// displacement SIZE*4 are ds_read offset immediates (<= ~11.8 KB).
// ---------------------------------------------------------------------------
template <int RES, int ENT>
__device__ __forceinline__ void dense_accum(const char* lds,
                                            float px, float py, float pz,
                                            float& a0, float& a1, float& a2)
{
    constexpr int SIZE = RES * RES * RES;
    constexpr float S = (float)(RES - 1);
    float fx = px * S, fy = py * S, fz = pz * S;

    // clip(floor(x),0,res-2) == floor(x) here, exactly (px in [0,1),
    // res-1 in [6,64]; the product never rounds up to res-1).
    float gx = floorf(fx), gy = floorf(fy), gz = floorf(fz);
    float wx = fx - gx, wy = fy - gy, wz = fz - gz;

    float lin = fmaf(gx, (float)(RES * RES * 4),
                 fmaf(gy, (float)(RES * 4),
                  fmaf(gz, 4.0f, (float)(ENT * 8))));
    unsigned a = (unsigned)lin;   // byte addr of this vertex's T01 slot

    float wx0 = 1.0f - wx, wy0 = 1.0f - wy, wz0 = 1.0f - wz;
    float w00 = wx0 * wy0, w01 = wx0 * wy, w10 = wx * wy0, w11 = wx * wy;

#define DCORNER(I, J, K, WT)                                                   \
    {                                                                          \
        constexpr int D4 = ((I) * RES * RES + (J) * RES + (K)) * 4;            \
        unsigned r01 = *reinterpret_cast<const unsigned*>(lds + a + D4);       \
        float    r2  = *reinterpret_cast<const float*>(                        \
                           lds + a + (D4 + SIZE * 4));                         \
        corner_accum(r01, r2, (WT), a0, a1, a2);                               \
    }

    // reference OFFSETS order: (i,j,k) for i in(0,1) j in(0,1) k in(0,1)
    DCORNER(0, 0, 0, w00 * wz0)
    DCORNER(0, 0, 1, w00 * wz)
    DCORNER(0, 1, 0, w01 * wz0)
    DCORNER(0, 1, 1, w01 * wz)
    DCORNER(1, 0, 0, w10 * wz0)
    DCORNER(1, 0, 1, w10 * wz)
    DCORNER(1, 1, 0, w11 * wz0)
    DCORNER(1, 1, 1, w11 * wz)
#undef DCORNER
}

// ---------------------------------------------------------------------------
// Hashed levels 4..9.  ENT = entry offset of this level.  Pow2 folds the *4
// byte-scale into the hash components ((h<<2) & ((SIZE-1)*4) == 4*(h&(SIZE-1)));
// non-pow2 uses the constexpr-divisor magic-mod.  Both reads share vaddr o4;
// level base and SIZE*4 ride in the offset immediates (max 34504 < 65536).
// ---------------------------------------------------------------------------
template <int SIZE, int ENT>
__device__ __forceinline__ void level_accum(const char* lds, int res,
                                            float px, float py, float pz,
                                            float& a0, float& a1, float& a2)
{
    constexpr bool POW2 = (SIZE & (SIZE - 1)) == 0;
    constexpr unsigned P1 = 2654435761u, P2 = 805459861u;

    const float s = (float)(res - 1);
    float fx = px * s, fy = py * s, fz = pz * s;

    float gx = floorf(fx), gy = floorf(fy), gz = floorf(fz);
    float wx = fx - gx, wy = fy - gy, wz = fz - gz;

    unsigned ux = (unsigned)(int)gx;
    unsigned uy = (unsigned)(int)gy;
    unsigned uz = (unsigned)(int)gz;

    unsigned hx0, hx1, hy0, hy1, hz0, hz1;
    if constexpr (POW2) {
        hx0 = ux << 2;        hx1 = hx0 + 4u;
        hy0 = uy * (P1 * 4u); hy1 = hy0 + (P1 * 4u);
        hz0 = uz * (P2 * 4u); hz1 = hz0 + (P2 * 4u);
    } else {
        hx0 = ux;       hx1 = ux + 1u;
        hy0 = uy * P1;  hy1 = hy0 + P1;
        hz0 = uz * P2;  hz1 = hz0 + P2;
    }
    unsigned h00 = hx0 ^ hy0, h01 = hx0 ^ hy1;
    unsigned h10 = hx1 ^ hy0, h11 = hx1 ^ hy1;

    float wx0 = 1.0f - wx, wy0 = 1.0f - wy, wz0 = 1.0f - wz;
    float w00 = wx0 * wy0, w01 = wx0 * wy, w10 = wx * wy0, w11 = wx * wy;

    auto corner = [&](unsigned h, float wt) {
        unsigned o4;
        if constexpr (POW2) o4 = h & (unsigned)((SIZE - 1) * 4);
        else                o4 = (h % (unsigned)SIZE) * 4u;  // magic mul
        unsigned r01 = *reinterpret_cast<const unsigned*>(
                           lds + (ENT * 8) + o4);
        float    r2  = *reinterpret_cast<const float*>(
                           lds + (ENT * 8 + SIZE * 4) + o4);
        corner_accum(r01, r2, wt, a0, a1, a2);
    };

    corner(h00 ^ hz0, w00 * wz0);
    corner(h00 ^ hz1, w00 * wz);
    corner(h01 ^ hz0, w01 * wz0);
    corner(h01 ^ hz1, w01 * wz);
    corner(h10 ^ hz0, w10 * wz0);
    corner(h10 ^ hz1, w10 * wz);
    corner(h11 ^ hz0, w11 * wz0);
    corner(h11 ^ hz1, w11 * wz);
}

// Write one staged entry into a level's dual tables.
template <int SIZE, int ENT>
__device__ __forceinline__ void stage_entry(char* lds, int idx,
                                            float s0, float s1, float s2)
{
    *reinterpret_cast<__half2*>(lds + ENT * 8 + idx * 4) =
        __floats2half2_rn(s0, s1);
    *reinterpret_cast<float*>(lds + ENT * 8 + SIZE * 4 + idx * 4) = s2;
}

// Stage one dense de-hashed grid: per vertex, hash+mod once, gather, store at
// the linear vertex index.  ~5 vertices/thread for 1024-thread blocks.
template <int RES, int SIZE, int ENT>
__device__ __forceinline__ void stage_dense(const float* __restrict__ src,
                                            char* lds)
{
    constexpr unsigned P1 = 2654435761u, P2 = 805459861u;
    constexpr int CUBE = RES * RES * RES;
    for (int v = threadIdx.x; v < CUBE; v += 1024) {
        int z = v % RES;
        int t = v / RES;
        int y = t % RES;
        int x = t / RES;
        unsigned h = (unsigned)x ^ ((unsigned)y * P1) ^ ((unsigned)z * P2);
        unsigned idx = h % (unsigned)SIZE;        // constexpr divisor
        const float* s = src + idx * 3;
        stage_entry<CUBE, ENT>(lds, v, s[0], s[1], s[2]);
    }
}

__global__ __launch_bounds__(1024, 8)
void hashgrid_kernel(const float* __restrict__ pts,
                     const float* __restrict__ c0, const float* __restrict__ c1,
                     const float* __restrict__ c2, const float* __restrict__ c3,
                     const float* __restrict__ c4, const float* __restrict__ c5,
                     const float* __restrict__ c6, const float* __restrict__ c7,
                     const float* __restrict__ c8, const float* __restrict__ c9,
                     float* __restrict__ out, int npts, ResArr res)
{
    __shared__ unsigned ldsbuf[TOTAL_ENTRIES * 2];   // 78040 B
    char* lds = reinterpret_cast<char*>(ldsbuf);

    // ---- stage hashed levels 4..9 (copy + compress f01, f2 as f32) ----
    {
        const float* s4 = c4; const float* s5 = c5; const float* s6 = c6;
        const float* s7 = c7; const float* s8 = c8; const float* s9 = c9;
        for (int e = threadIdx.x; e < 324; e += 1024)
            stage_entry< 324,    0>(lds, e, s4[e*3], s4[e*3+1], s4[e*3+2]);
        for (int e = threadIdx.x; e < 529; e += 1024)
            stage_entry< 529,  324>(lds, e, s5[e*3], s5[e*3+1], s5[e*3+2]);
        for (int e = threadIdx.x; e < 900; e += 1024)
            stage_entry< 900,  853>(lds, e, s6[e*3], s6[e*3+1], s6[e*3+2]);
        for (int e = threadIdx.x; e < 1024; e += 1024)
            stage_entry<1024, 1753>(lds, e, s7[e*3], s7[e*3+1], s7[e*3+2]);
        for (int e = threadIdx.x; e < 1024; e += 1024)
            stage_entry<1024, 2777>(lds, e, s8[e*3], s8[e*3+1], s8[e*3+2]);
        for (int e = threadIdx.x; e < 1024; e += 1024)
            stage_entry<1024, 3801>(lds, e, s9[e*3], s9[e*3+1], s9[e*3+2]);
    }
    // ---- stage dense de-hashed grids, levels 0..3 ----
    stage_dense< 7,  49, 4825>(c0, lds);
    stage_dense< 8,  64, 5168>(c1, lds);
    stage_dense<11, 121, 5680>(c2, lds);
    stage_dense<14, 196, 7011>(c3, lds);
    __syncthreads();

    // 512 blocks x 1024 thr (2 blocks/CU, 32 waves/CU), 2 points/thread/iter,
    // 2 iterations for npts = 2M.  Immediate-consume corner structure -- the
    // compiler's own schedule is the best available (R2/R3/R6 evidence).
    const int S = gridDim.x * blockDim.x;
    for (int n = blockIdx.x * blockDim.x + threadIdx.x; n < npts; n += 2 * S) {
        const int m = n + S;
        const bool hasB = (m < npts);
        const int mc = hasB ? m : n;      // clamp: B duplicates A, store suppressed

        float ax = pts[n * 3 + 0], ay = pts[n * 3 + 1], az = pts[n * 3 + 2];
        float bx = pts[mc * 3 + 0], by = pts[mc * 3 + 1], bz = pts[mc * 3 + 2];

        float A0 = 0.0f, A1 = 0.0f, A2 = 0.0f;
        float B0 = 0.0f, B1 = 0.0f, B2 = 0.0f;

        // levels 0..3: dense de-hashed grids (no hash, no modulo; level base
        // folded into the float address chain)
#define DLEVEL2(RES, ENT)                                        \
        dense_accum<RES, ENT>(lds, ax, ay, az, A0, A1, A2);      \
        dense_accum<RES, ENT>(lds, bx, by, bz, B0, B1, B2);

        DLEVEL2( 7, 4825)
        DLEVEL2( 8, 5168)
        DLEVEL2(11, 5680)
        DLEVEL2(14, 7011)
#undef DLEVEL2

        // levels 4..9: hashed lookups (magic-mod for 324/529/900, masked
        // pow2 for the 1024s)
#define HLEVEL2(SZ, ENT, HL)                                                  \
        level_accum<SZ, ENT>(lds, res.r[(HL) + 4], ax, ay, az, A0, A1, A2);   \
        level_accum<SZ, ENT>(lds, res.r[(HL) + 4], bx, by, bz, B0, B1, B2);

        HLEVEL2( 324,    0, 0)
        HLEVEL2( 529,  324, 1)
        HLEVEL2( 900,  853, 2)
        HLEVEL2(1024, 1753, 3)
        HLEVEL2(1024, 2777, 4)
        HLEVEL2(1024, 3801, 5)
#undef HLEVEL2

        out[n * 3 + 0] = A0;
        out[n * 3 + 1] = A1;
        out[n * 3 + 2] = A2;
        if (hasB) {
            out[m * 3 + 0] = B0;
            out[m * 3 + 1] = B1;
            out[m * 3 + 2] = B2;
        }
    }
}

extern "C" void kernel_launch(void* const* d_in, const int* in_sizes, int n_in,
                              void* d_out, int out_size, void* d_ws, size_t ws_size,
                              hipStream_t stream)
{
    const float* pts = (const float*)d_in[0];
    const int npts = in_sizes[0] / 3;

    // Replicate numpy's exact double-precision LOD computation (glibc libm):
    // LOD 9 sits at 6*b^9 == 64.0 +/- ~1e-14, floor() is boundary-sensitive.
    // (Only levels 4..9 are consumed at runtime; 0..3 are compile-time dense.)
    ResArr ra;
    const double b = exp((log(64.0) - log(6.0)) / 9.0);
    for (int l = 0; l < NLOD; ++l)
        ra.r[l] = (int)(1.0 + floor(6.0 * pow(b, (double)l)));

    // 512 blocks x 1024 thr: 2 blocks/CU (156 KB LDS), 32 waves/CU.
    hashgrid_kernel<<<dim3(512), dim3(1024), 0, stream>>>(
        pts,
        (const float*)d_in[1], (const float*)d_in[2], (const float*)d_in[3],
        (const float*)d_in[4], (const float*)d_in[5], (const float*)d_in[6],
        (const float*)d_in[7], (const float*)d_in[8], (const float*)d_in[9],
        (const float*)d_in[10],
        (float*)d_out, npts, ra);
}

// Round 8
// 138.617 us; speedup vs baseline: 1.5274x; 1.5274x over previous
//
#include <hip/hip_runtime.h>
#include <hip/hip_fp16.h>
#include <cmath>

#define NLOD 10

// ---------------------------------------------------------------------------
// LDS layout (all compile-time):
//   [hashed levels 4..9]  4825 entries   bytes      0 .. 38600
//   [dense grids 0..3]    4930 vertices  bytes  38600 .. 78040
// Hashed levels come FIRST so every ds_read offset immediate (level base +
// corner delta) stays < 65536.  78040 B/block -> two 1024-thread blocks/CU
// (156 KB of 160 KB), 32 waves/CU = the hardware wave cap.
//
// Levels 0..3 are staged DE-HASHED: the per-vertex hash+mod is computed once
// per block at staging (4930 vertices), and the hot loop addresses them by
// linear vertex coordinate -> no hash, no magic-modulo, no per-corner
// address math (corner deltas fold into ds_read offset immediates).
//
// SESSION VERDICT (rounds 2-7): this immediate-consume AoS-b64 form is the
// optimum reachable under hipcc.
//  - Source-phased loads: spill at 64-VGPR cap (R3: +27 MB HBM scratch) and
//    get re-serialized at 128-VGPR cap (R6: VGPR stays 32, 8% slower at
//    16 waves/CU).
//  - SoA half2+u16 split: sub-dword LDS reads serialize in the banks
//    (R4: conflicts 1.6e7 -> 2.4e7, dur +28%).
//  - Dual 4B dword tables: conflicts UP again (2.45e7) plus pathological
//    ~500 MB/dispatch HBM traffic (R7: dur 135 us).
// Both pipes sit at ~70% (VALU ~98K cyc/CU, LDS ~102K cyc/CU incl. 63K
// conflict cycles); overlap of the remaining bubbles is compiler-owned.
// ---------------------------------------------------------------------------
static constexpr int HSIZES[6] = {324, 529, 900, 1024, 1024, 1024}; // levels 4..9
static constexpr int HENT[6]   = {0, 324, 853, 1753, 2777, 3801};   // entry offsets
static constexpr int TOTAL_ENTRIES = 9755;                           // 4825 + 4930
// LDS bytes = 9755 * 8 = 78040

struct ResArr { int r[NLOD]; };

// One ds_read_b64 per corner; three v_fma_mix_f32 consume the f16 halves in
// place via op_sel (numerically identical to fpext+fma, both exact/fused).
__device__ __forceinline__ void fmix_accum(uint2 raw, float wt,
                                           float& a0, float& a1, float& a2)
{
    asm("v_fma_mix_f32 %0, %1, %2, %0 op_sel_hi:[1,0,0]"
        : "+v"(a0) : "v"(raw.x), "v"(wt));
    asm("v_fma_mix_f32 %0, %1, %2, %0 op_sel:[1,0,0] op_sel_hi:[1,0,0]"
        : "+v"(a1) : "v"(raw.x), "v"(wt));
    asm("v_fma_mix_f32 %0, %1, %2, %0 op_sel_hi:[1,0,0]"
        : "+v"(a2) : "v"(raw.y), "v"(wt));
}

// ---------------------------------------------------------------------------
// Dense (de-hashed) levels 0..3.  LBASE = byte offset of this level's grid.
// Address math is 2 fma + cvt: lin = ((gx*RES+gy)*RES+gz)*8 is an exact
// integer-valued float (all terms < 2^24), corner deltas are constant
// immediates on the ds_read.
// ---------------------------------------------------------------------------
template <int RES, int LBASE>
__device__ __forceinline__ void dense_accum(const char* lds,
                                            float px, float py, float pz,
                                            float& a0, float& a1, float& a2)
{
    constexpr float S = (float)(RES - 1);
    float fx = px * S, fy = py * S, fz = pz * S;

    // clip(floor(x),0,res-2) == floor(x) here, exactly (px in [0,1),
    // res-1 in [6,64]; the product never rounds up to res-1).
    float gx = floorf(fx), gy = floorf(fy), gz = floorf(fz);
    float wx = fx - gx, wy = fy - gy, wz = fz - gz;

    float lin = fmaf(gx, (float)(RES * RES * 8),
                 fmaf(gy, (float)(RES * 8), gz * 8.0f));
    unsigned base = (unsigned)lin;   // exact: lin is a non-negative integer

    float wx0 = 1.0f - wx, wy0 = 1.0f - wy, wz0 = 1.0f - wz;
    float w00 = wx0 * wy0, w01 = wx0 * wy, w10 = wx * wy0, w11 = wx * wy;

#define DCORNER(I, J, K, WT)                                                   \
    fmix_accum(*reinterpret_cast<const uint2*>(                                \
                   lds + base + (LBASE + ((I)*RES*RES + (J)*RES + (K)) * 8)),  \
               (WT), a0, a1, a2);

    // reference OFFSETS order: (i,j,k) for i in(0,1) j in(0,1) k in(0,1)
    DCORNER(0, 0, 0, w00 * wz0)
    DCORNER(0, 0, 1, w00 * wz)
    DCORNER(0, 1, 0, w01 * wz0)
    DCORNER(0, 1, 1, w01 * wz)
    DCORNER(1, 0, 0, w10 * wz0)
    DCORNER(1, 0, 1, w10 * wz)
    DCORNER(1, 1, 0, w11 * wz0)
    DCORNER(1, 1, 1, w11 * wz)
#undef DCORNER
}

// ---------------------------------------------------------------------------
// Hashed levels 4..9.
// ---------------------------------------------------------------------------
template <int SIZE>
__device__ __forceinline__ void level_accum(const __half* __restrict__ cb, int res,
                                            float px, float py, float pz,
                                            float& a0, float& a1, float& a2)
{
    constexpr bool POW2 = (SIZE & (SIZE - 1)) == 0;
    constexpr unsigned P1 = 2654435761u, P2 = 805459861u;

    const float s = (float)(res - 1);
    float fx = px * s, fy = py * s, fz = pz * s;

    float gx = floorf(fx), gy = floorf(fy), gz = floorf(fz);
    float wx = fx - gx, wy = fy - gy, wz = fz - gz;

    unsigned ux = (unsigned)(int)gx;
    unsigned uy = (unsigned)(int)gy;
    unsigned uz = (unsigned)(int)gz;

    // Incremental hash terms: h = (x*1) ^ (y*P1) ^ (z*P2).
    // For pow2 SIZE fold the *8 byte-scale into the components
    // ((h<<3) mod (8*SIZE) == 8*(h mod SIZE) iff SIZE is pow2).
    unsigned hx0, hx1, hy0, hy1, hz0, hz1;
    if constexpr (POW2) {
        hx0 = ux << 3;        hx1 = hx0 + 8u;
        hy0 = uy * (P1 * 8u); hy1 = hy0 + (P1 * 8u);
        hz0 = uz * (P2 * 8u); hz1 = hz0 + (P2 * 8u);
    } else {
        hx0 = ux;       hx1 = ux + 1u;
        hy0 = uy * P1;  hy1 = hy0 + P1;
        hz0 = uz * P2;  hz1 = hz0 + P2;
    }
    unsigned h00 = hx0 ^ hy0, h01 = hx0 ^ hy1;
    unsigned h10 = hx1 ^ hy0, h11 = hx1 ^ hy1;

    float wx0 = 1.0f - wx, wy0 = 1.0f - wy, wz0 = 1.0f - wz;
    float w00 = wx0 * wy0, w01 = wx0 * wy, w10 = wx * wy0, w11 = wx * wy;

    auto corner = [&](unsigned h, float wt) {
        uint2 raw;
        if constexpr (POW2) {
            unsigned addr = h & (unsigned)((SIZE - 1) * 8);
            raw = *reinterpret_cast<const uint2*>(
                      reinterpret_cast<const char*>(cb) + addr);
        } else {
            unsigned idx = h % (unsigned)SIZE;   // constexpr divisor -> magic mul
            raw = reinterpret_cast<const uint2*>(cb)[idx];
        }
        fmix_accum(raw, wt, a0, a1, a2);
    };

    corner(h00 ^ hz0, w00 * wz0);
    corner(h00 ^ hz1, w00 * wz);
    corner(h01 ^ hz0, w01 * wz0);
    corner(h01 ^ hz1, w01 * wz);
    corner(h10 ^ hz0, w10 * wz0);
    corner(h10 ^ hz1, w10 * wz);
    corner(h11 ^ hz0, w11 * wz0);
    corner(h11 ^ hz1, w11 * wz);
}

// Stage one dense de-hashed grid: per vertex (x,y,z), compute the Instant-NGP
// hash once, gather the codebook entry, compress to f16, store at the linear
// vertex index.  ~5 vertices/thread for 1024-thread blocks.
template <int RES, int SIZE, int ENT>
__device__ __forceinline__ void stage_dense(const float* __restrict__ src,
                                            __half* cbh)
{
    constexpr unsigned P1 = 2654435761u, P2 = 805459861u;
    for (int v = threadIdx.x; v < RES * RES * RES; v += 1024) {
        int z = v % RES;
        int t = v / RES;
        int y = t % RES;
        int x = t / RES;
        unsigned h = (unsigned)x ^ ((unsigned)y * P1) ^ ((unsigned)z * P2);
        unsigned idx = h % (unsigned)SIZE;        // constexpr divisor
        const float* s = src + idx * 3;
        __half2* d = reinterpret_cast<__half2*>(cbh + (ENT + v) * 4);
        d[0] = __floats2half2_rn(s[0], s[1]);
        d[1] = __floats2half2_rn(s[2], 0.0f);
    }
}

__global__ __launch_bounds__(1024, 8)
void hashgrid_kernel(const float* __restrict__ pts,
                     const float* __restrict__ c0, const float* __restrict__ c1,
                     const float* __restrict__ c2, const float* __restrict__ c3,
                     const float* __restrict__ c4, const float* __restrict__ c5,
                     const float* __restrict__ c6, const float* __restrict__ c7,
                     const float* __restrict__ c8, const float* __restrict__ c9,
                     float* __restrict__ out, int npts, ResArr res)
{
    __shared__ __half cbh[TOTAL_ENTRIES * 4];   // 78040 B
    const char* lds = reinterpret_cast<const char*>(cbh);

    // ---- stage hashed levels 4..9 (copy + compress) ----
    {
        const float* hs[6] = {c4, c5, c6, c7, c8, c9};
#pragma unroll
        for (int L = 0; L < 6; ++L) {
            for (int e = threadIdx.x; e < HSIZES[L]; e += 1024) {
                const float* s = hs[L] + e * 3;
                __half2* d = reinterpret_cast<__half2*>(cbh + (HENT[L] + e) * 4);
                d[0] = __floats2half2_rn(s[0], s[1]);
                d[1] = __floats2half2_rn(s[2], 0.0f);
            }
        }
    }
    // ---- stage dense de-hashed grids, levels 0..3 ----
    stage_dense< 7,  49, 4825>(c0, cbh);
    stage_dense< 8,  64, 5168>(c1, cbh);
    stage_dense<11, 121, 5680>(c2, cbh);
    stage_dense<14, 196, 7011>(c3, cbh);
    __syncthreads();

    // 512 blocks x 1024 thr (exactly 2 blocks/CU), 2 points/thread/iter,
    // 2 iterations for npts = 2M.  Immediate-consume corner structure: the
    // compiler's own schedule is the best available (R2/R3/R6 evidence).
    const int S = gridDim.x * blockDim.x;
    for (int n = blockIdx.x * blockDim.x + threadIdx.x; n < npts; n += 2 * S) {
        const int m = n + S;
        const bool hasB = (m < npts);
        const int mc = hasB ? m : n;      // clamp: B duplicates A, store suppressed

        float ax = pts[n * 3 + 0], ay = pts[n * 3 + 1], az = pts[n * 3 + 2];
        float bx = pts[mc * 3 + 0], by = pts[mc * 3 + 1], bz = pts[mc * 3 + 2];

        float A0 = 0.0f, A1 = 0.0f, A2 = 0.0f;
        float B0 = 0.0f, B1 = 0.0f, B2 = 0.0f;

        // levels 0..3: dense de-hashed grids (no hash, no modulo; corner
        // deltas are ds_read offset immediates)
#define DLEVEL2(RES, ENT)                                       \
        dense_accum<RES, (ENT) * 8>(lds, ax, ay, az, A0, A1, A2); \
        dense_accum<RES, (ENT) * 8>(lds, bx, by, bz, B0, B1, B2);

        DLEVEL2( 7, 4825)
        DLEVEL2( 8, 5168)
        DLEVEL2(11, 5680)
        DLEVEL2(14, 7011)
#undef DLEVEL2

        // levels 4..9: hashed lookups (magic-mod for 324/529/900, masked
        // pow2 for the 1024s)
#define HLEVEL2(SZ, HL)                                                               \
        level_accum<SZ>(cbh + HENT[HL] * 4, res.r[(HL) + 4], ax, ay, az, A0, A1, A2); \
        level_accum<SZ>(cbh + HENT[HL] * 4, res.r[(HL) + 4], bx, by, bz, B0, B1, B2);

        HLEVEL2( 324, 0)
        HLEVEL2( 529, 1)
        HLEVEL2( 900, 2)
        HLEVEL2(1024, 3)
        HLEVEL2(1024, 4)
        HLEVEL2(1024, 5)
#undef HLEVEL2

        out[n * 3 + 0] = A0;
        out[n * 3 + 1] = A1;
        out[n * 3 + 2] = A2;
        if (hasB) {
            out[m * 3 + 0] = B0;
            out[m * 3 + 1] = B1;
            out[m * 3 + 2] = B2;
        }
    }
}

extern "C" void kernel_launch(void* const* d_in, const int* in_sizes, int n_in,
                              void* d_out, int out_size, void* d_ws, size_t ws_size,
                              hipStream_t stream)
{
    const float* pts = (const float*)d_in[0];
    const int npts = in_sizes[0] / 3;

    // Replicate numpy's exact double-precision LOD computation (glibc libm):
    // LOD 9 sits at 6*b^9 == 64.0 +/- ~1e-14, floor() is boundary-sensitive.
    // (Only levels 4..9 are consumed at runtime; 0..3 are compile-time dense.)
    ResArr ra;
    const double b = exp((log(64.0) - log(6.0)) / 9.0);
    for (int l = 0; l < NLOD; ++l)
        ra.r[l] = (int)(1.0 + floor(6.0 * pow(b, (double)l)));

    // 512 blocks x 1024 thr: 2 blocks/CU (156 KB LDS), 32 waves/CU.
    hashgrid_kernel<<<dim3(512), dim3(1024), 0, stream>>>(
        pts,
        (const float*)d_in[1], (const float*)d_in[2], (const float*)d_in[3],
        (const float*)d_in[4], (const float*)d_in[5], (const float*)d_in[6],
        (const float*)d_in[7], (const float*)d_in[8], (const float*)d_in[9],
        (const float*)d_in[10],
        (float*)d_out, npts, ra);
}

// Round 9
// 136.724 us; speedup vs baseline: 1.5486x; 1.0138x over previous
//
#include <hip/hip_runtime.h>
#include <hip/hip_fp16.h>
#include <cmath>

#define NLOD 10

// ---------------------------------------------------------------------------
// Hybrid gather (round-8 decision): levels 0..8 from LDS, level 9 from
// GLOBAL memory (f32, L1-resident).
//
// Rationale: the LDS pipe is the binding resource (~102K cyc/CU; 62% is the
// random-gather conflict tail that two layout interventions -- R4 sub-dword
// SoA, R7 dual-4B tables -- both made WORSE, so it is treated as
// irreducible for 8 B entries).  The vector-memory pipe is ~idle (35 MB
// HBM traffic / 58 us).  Level 9's codebook is 1024 x 3 f32 = 12 KB ->
// fully L1-cacheable per CU (all waves share it).  Moving its 8
// gathers/point to global_load_dwordx3 removes 10% of LDS-pipe pressure
// and pays on the idle pipe, hidden by the same 32-wave TLP.  f32 features
// for this level are EXACT (accuracy can only improve vs f16).
//
// LDS layout (AoS 8 B entries, immediate-consume -- the verified optimum
// form from rounds 1-8):
//   [hashed levels 4..8]  3801 entries   bytes      0 .. 30408
//   [dense grids 0..3]    4930 vertices  bytes  30408 .. 69848
// 69848 B/block -> two 1024-thread blocks/CU, 32 waves/CU (hardware cap).
//
// Levels 0..3 are staged DE-HASHED (hash+mod once per vertex at staging;
// hot loop addresses by linear vertex coordinate, corner deltas fold into
// ds_read offset immediates; all immediates < 65536).
//
// Scheduling lessons kept (R2/R3/R6): no source-phased load arrays -- hipcc
// spills at 64-VGPR cap and re-serializes at 128; immediate-consume + full
// occupancy wins.
// ---------------------------------------------------------------------------
static constexpr int HSIZES[5] = {324, 529, 900, 1024, 1024};  // levels 4..8
static constexpr int HENT[5]   = {0, 324, 853, 1753, 2777};    // entry offsets
static constexpr int TOTAL_ENTRIES = 8731;                      // 3801 + 4930
// dense grids: res 7,8,11,14 -> cubes 343,512,1331,2744; entry offsets:
//   3801, 4144, 4656, 5987.   LDS bytes = 8731 * 8 = 69848.

struct ResArr { int r[NLOD]; };

// One ds_read_b64 per corner; three v_fma_mix_f32 consume the f16 halves in
// place via op_sel (numerically identical to fpext+fma, both exact/fused).
__device__ __forceinline__ void fmix_accum(uint2 raw, float wt,
                                           float& a0, float& a1, float& a2)
{
    asm("v_fma_mix_f32 %0, %1, %2, %0 op_sel_hi:[1,0,0]"
        : "+v"(a0) : "v"(raw.x), "v"(wt));
    asm("v_fma_mix_f32 %0, %1, %2, %0 op_sel:[1,0,0] op_sel_hi:[1,0,0]"
        : "+v"(a1) : "v"(raw.x), "v"(wt));
    asm("v_fma_mix_f32 %0, %1, %2, %0 op_sel_hi:[1,0,0]"
        : "+v"(a2) : "v"(raw.y), "v"(wt));
}

// ---------------------------------------------------------------------------
// Dense (de-hashed) levels 0..3.  LBASE = byte offset of this level's grid.
// Address math is 2 fma + cvt: lin = ((gx*RES+gy)*RES+gz)*8 is an exact
// integer-valued float (all terms < 2^24); corner deltas + LBASE are
// constant immediates on the ds_read (max 49584 < 65536).
// ---------------------------------------------------------------------------
template <int RES, int LBASE>
__device__ __forceinline__ void dense_accum(const char* lds,
                                            float px, float py, float pz,
                                            float& a0, float& a1, float& a2)
{
    constexpr float S = (float)(RES - 1);
    float fx = px * S, fy = py * S, fz = pz * S;

    // clip(floor(x),0,res-2) == floor(x) here, exactly (px in [0,1),
    // res-1 in [6,64]; the product never rounds up to res-1).
    float gx = floorf(fx), gy = floorf(fy), gz = floorf(fz);
    float wx = fx - gx, wy = fy - gy, wz = fz - gz;

    float lin = fmaf(gx, (float)(RES * RES * 8),
                 fmaf(gy, (float)(RES * 8), gz * 8.0f));
    unsigned base = (unsigned)lin;   // exact: lin is a non-negative integer

    float wx0 = 1.0f - wx, wy0 = 1.0f - wy, wz0 = 1.0f - wz;
    float w00 = wx0 * wy0, w01 = wx0 * wy, w10 = wx * wy0, w11 = wx * wy;

#define DCORNER(I, J, K, WT)                                                   \
    fmix_accum(*reinterpret_cast<const uint2*>(                                \
                   lds + base + (LBASE + ((I)*RES*RES + (J)*RES + (K)) * 8)),  \
               (WT), a0, a1, a2);

    // reference OFFSETS order: (i,j,k) for i in(0,1) j in(0,1) k in(0,1)
    DCORNER(0, 0, 0, w00 * wz0)
    DCORNER(0, 0, 1, w00 * wz)
    DCORNER(0, 1, 0, w01 * wz0)
    DCORNER(0, 1, 1, w01 * wz)
    DCORNER(1, 0, 0, w10 * wz0)
    DCORNER(1, 0, 1, w10 * wz)
    DCORNER(1, 1, 0, w11 * wz0)
    DCORNER(1, 1, 1, w11 * wz)
#undef DCORNER
}

// ---------------------------------------------------------------------------
// Hashed LDS levels 4..8.
// ---------------------------------------------------------------------------
template <int SIZE>
__device__ __forceinline__ void level_accum(const __half* __restrict__ cb, int res,
                                            float px, float py, float pz,
                                            float& a0, float& a1, float& a2)
{
    constexpr bool POW2 = (SIZE & (SIZE - 1)) == 0;
    constexpr unsigned P1 = 2654435761u, P2 = 805459861u;

    const float s = (float)(res - 1);
    float fx = px * s, fy = py * s, fz = pz * s;

    float gx = floorf(fx), gy = floorf(fy), gz = floorf(fz);
    float wx = fx - gx, wy = fy - gy, wz = fz - gz;

    unsigned ux = (unsigned)(int)gx;
    unsigned uy = (unsigned)(int)gy;
    unsigned uz = (unsigned)(int)gz;

    // Incremental hash terms: h = (x*1) ^ (y*P1) ^ (z*P2).
    // For pow2 SIZE fold the *8 byte-scale into the components
    // ((h<<3) mod (8*SIZE) == 8*(h mod SIZE) iff SIZE is pow2).
    unsigned hx0, hx1, hy0, hy1, hz0, hz1;
    if constexpr (POW2) {
        hx0 = ux << 3;        hx1 = hx0 + 8u;
        hy0 = uy * (P1 * 8u); hy1 = hy0 + (P1 * 8u);
        hz0 = uz * (P2 * 8u); hz1 = hz0 + (P2 * 8u);
    } else {
        hx0 = ux;       hx1 = ux + 1u;
        hy0 = uy * P1;  hy1 = hy0 + P1;
        hz0 = uz * P2;  hz1 = hz0 + P2;
    }
    unsigned h00 = hx0 ^ hy0, h01 = hx0 ^ hy1;
    unsigned h10 = hx1 ^ hy0, h11 = hx1 ^ hy1;

    float wx0 = 1.0f - wx, wy0 = 1.0f - wy, wz0 = 1.0f - wz;
    float w00 = wx0 * wy0, w01 = wx0 * wy, w10 = wx * wy0, w11 = wx * wy;

    auto corner = [&](unsigned h, float wt) {
        uint2 raw;
        if constexpr (POW2) {
            unsigned addr = h & (unsigned)((SIZE - 1) * 8);
            raw = *reinterpret_cast<const uint2*>(
                      reinterpret_cast<const char*>(cb) + addr);
        } else {
            unsigned idx = h % (unsigned)SIZE;   // constexpr divisor -> magic mul
            raw = reinterpret_cast<const uint2*>(cb)[idx];
        }
        fmix_accum(raw, wt, a0, a1, a2);
    };

    corner(h00 ^ hz0, w00 * wz0);
    corner(h00 ^ hz1, w00 * wz);
    corner(h01 ^ hz0, w01 * wz0);
    corner(h01 ^ hz1, w01 * wz);
    corner(h10 ^ hz0, w10 * wz0);
    corner(h10 ^ hz1, w10 * wz);
    corner(h11 ^ hz0, w11 * wz0);
    corner(h11 ^ hz1, w11 * wz);
}

// ---------------------------------------------------------------------------
// Level 9 from GLOBAL (1024-entry f32 codebook, 12 KB, L1-resident).
// Same hash; gather 12 B/corner via dwordx3; exact f32 fma accumulate.
// ---------------------------------------------------------------------------
__device__ __forceinline__ void gl9_accum(const float* __restrict__ cb, int res,
                                          float px, float py, float pz,
                                          float& a0, float& a1, float& a2)
{
    constexpr unsigned P1 = 2654435761u, P2 = 805459861u;

    const float s = (float)(res - 1);
    float fx = px * s, fy = py * s, fz = pz * s;

    float gx = floorf(fx), gy = floorf(fy), gz = floorf(fz);
    float wx = fx - gx, wy = fy - gy, wz = fz - gz;

    unsigned ux = (unsigned)(int)gx;
    unsigned uy = (unsigned)(int)gy;
    unsigned uz = (unsigned)(int)gz;

    unsigned hx0 = ux,      hx1 = ux + 1u;
    unsigned hy0 = uy * P1, hy1 = hy0 + P1;
    unsigned hz0 = uz * P2, hz1 = hz0 + P2;
    unsigned h00 = hx0 ^ hy0, h01 = hx0 ^ hy1;
    unsigned h10 = hx1 ^ hy0, h11 = hx1 ^ hy1;

    float wx0 = 1.0f - wx, wy0 = 1.0f - wy, wz0 = 1.0f - wz;
    float w00 = wx0 * wy0, w01 = wx0 * wy, w10 = wx * wy0, w11 = wx * wy;

    auto corner = [&](unsigned h, float wt) {
        unsigned idx = h & 1023u;            // SIZE = 1024
        const float* e = cb + idx * 3u;      // dwordx3 gather, L1-hit
        float f0 = e[0], f1 = e[1], f2 = e[2];
        a0 = fmaf(f0, wt, a0);
        a1 = fmaf(f1, wt, a1);
        a2 = fmaf(f2, wt, a2);
    };

    corner(h00 ^ hz0, w00 * wz0);
    corner(h00 ^ hz1, w00 * wz);
    corner(h01 ^ hz0, w01 * wz0);
    corner(h01 ^ hz1, w01 * wz);
    corner(h10 ^ hz0, w10 * wz0);
    corner(h10 ^ hz1, w10 * wz);
    corner(h11 ^ hz0, w11 * wz0);
    corner(h11 ^ hz1, w11 * wz);
}

// Stage one dense de-hashed grid: per vertex (x,y,z), compute the Instant-NGP
// hash once, gather the codebook entry, compress to f16, store at the linear
// vertex index.  ~5 vertices/thread for 1024-thread blocks.
template <int RES, int SIZE, int ENT>
__device__ __forceinline__ void stage_dense(const float* __restrict__ src,
                                            __half* cbh)
{
    constexpr unsigned P1 = 2654435761u, P2 = 805459861u;
    for (int v = threadIdx.x; v < RES * RES * RES; v += 1024) {
        int z = v % RES;
        int t = v / RES;
        int y = t % RES;
        int x = t / RES;
        unsigned h = (unsigned)x ^ ((unsigned)y * P1) ^ ((unsigned)z * P2);
        unsigned idx = h % (unsigned)SIZE;        // constexpr divisor
        const float* s = src + idx * 3;
        __half2* d = reinterpret_cast<__half2*>(cbh + (ENT + v) * 4);
        d[0] = __floats2half2_rn(s[0], s[1]);
        d[1] = __floats2half2_rn(s[2], 0.0f);
    }
}

__global__ __launch_bounds__(1024, 8)
void hashgrid_kernel(const float* __restrict__ pts,
                     const float* __restrict__ c0, const float* __restrict__ c1,
                     const float* __restrict__ c2, const float* __restrict__ c3,
                     const float* __restrict__ c4, const float* __restrict__ c5,
                     const float* __restrict__ c6, const float* __restrict__ c7,
                     const float* __restrict__ c8, const float* __restrict__ c9,
                     float* __restrict__ out, int npts, ResArr res)
{
    __shared__ __half cbh[TOTAL_ENTRIES * 4];   // 69848 B
    const char* lds = reinterpret_cast<const char*>(cbh);

    // ---- stage hashed levels 4..8 (copy + compress) ----
    {
        const float* hs[5] = {c4, c5, c6, c7, c8};
#pragma unroll
        for (int L = 0; L < 5; ++L) {
            for (int e = threadIdx.x; e < HSIZES[L]; e += 1024) {
                const float* s = hs[L] + e * 3;
                __half2* d = reinterpret_cast<__half2*>(cbh + (HENT[L] + e) * 4);
                d[0] = __floats2half2_rn(s[0], s[1]);
                d[1] = __floats2half2_rn(s[2], 0.0f);
            }
        }
    }
    // ---- stage dense de-hashed grids, levels 0..3 ----
    stage_dense< 7,  49, 3801>(c0, cbh);
    stage_dense< 8,  64, 4144>(c1, cbh);
    stage_dense<11, 121, 4656>(c2, cbh);
    stage_dense<14, 196, 5987>(c3, cbh);
    __syncthreads();

    // 512 blocks x 1024 thr (exactly 2 blocks/CU, 32 waves/CU),
    // 2 points/thread/iter, 2 iterations for npts = 2M.
    const int S = gridDim.x * blockDim.x;
    const int r9 = res.r[9];
    for (int n = blockIdx.x * blockDim.x + threadIdx.x; n < npts; n += 2 * S) {
        const int m = n + S;
        const bool hasB = (m < npts);
        const int mc = hasB ? m : n;      // clamp: B duplicates A, store suppressed

        float ax = pts[n * 3 + 0], ay = pts[n * 3 + 1], az = pts[n * 3 + 2];
        float bx = pts[mc * 3 + 0], by = pts[mc * 3 + 1], bz = pts[mc * 3 + 2];

        float A0 = 0.0f, A1 = 0.0f, A2 = 0.0f;
        float B0 = 0.0f, B1 = 0.0f, B2 = 0.0f;

        // level 9 first: its global loads issue earliest, L1-hit latency
        // hides under the 9 LDS levels that follow (vector pipe is idle).
        gl9_accum(c9, r9, ax, ay, az, A0, A1, A2);
        gl9_accum(c9, r9, bx, by, bz, B0, B1, B2);

        // levels 0..3: dense de-hashed grids (no hash, no modulo; corner
        // deltas are ds_read offset immediates)
#define DLEVEL2(RES, ENT)                                       \
        dense_accum<RES, (ENT) * 8>(lds, ax, ay, az, A0, A1, A2); \
        dense_accum<RES, (ENT) * 8>(lds, bx, by, bz, B0, B1, B2);

        DLEVEL2( 7, 3801)
        DLEVEL2( 8, 4144)
        DLEVEL2(11, 4656)
        DLEVEL2(14, 5987)
#undef DLEVEL2

        // levels 4..8: hashed LDS lookups (magic-mod for 324/529/900,
        // masked pow2 for the 1024s)
#define HLEVEL2(SZ, HL)                                                               \
        level_accum<SZ>(cbh + HENT[HL] * 4, res.r[(HL) + 4], ax, ay, az, A0, A1, A2); \
        level_accum<SZ>(cbh + HENT[HL] * 4, res.r[(HL) + 4], bx, by, bz, B0, B1, B2);

        HLEVEL2( 324, 0)
        HLEVEL2( 529, 1)
        HLEVEL2( 900, 2)
        HLEVEL2(1024, 3)
        HLEVEL2(1024, 4)
#undef HLEVEL2

        out[n * 3 + 0] = A0;
        out[n * 3 + 1] = A1;
        out[n * 3 + 2] = A2;
        if (hasB) {
            out[m * 3 + 0] = B0;
            out[m * 3 + 1] = B1;
            out[m * 3 + 2] = B2;
        }
    }
}

extern "C" void kernel_launch(void* const* d_in, const int* in_sizes, int n_in,
                              void* d_out, int out_size, void* d_ws, size_t ws_size,
                              hipStream_t stream)
{
    const float* pts = (const float*)d_in[0];
    const int npts = in_sizes[0] / 3;

    // Replicate numpy's exact double-precision LOD computation (glibc libm):
    // LOD 9 sits at 6*b^9 == 64.0 +/- ~1e-14, floor() is boundary-sensitive.
    ResArr ra;
    const double b = exp((log(64.0) - log(6.0)) / 9.0);
    for (int l = 0; l < NLOD; ++l)
        ra.r[l] = (int)(1.0 + floor(6.0 * pow(b, (double)l)));

    // 512 blocks x 1024 thr: 2 blocks/CU (~140 KB LDS), 32 waves/CU.
    hashgrid_kernel<<<dim3(512), dim3(1024), 0, stream>>>(
        pts,
        (const float*)d_in[1], (const float*)d_in[2], (const float*)d_in[3],
        (const float*)d_in[4], (const float*)d_in[5], (const float*)d_in[6],
        (const float*)d_in[7], (const float*)d_in[8], (const float*)d_in[9],
        (const float*)d_in[10],
        (float*)d_out, npts, ra);
}